// Round 25
// baseline (677.685 us; speedup 1.0000x reference)
//
#include <hip/hip_runtime.h>
#include <hip/hip_bf16.h>
#include <cmath>

#define LAYERS 4
#define Bb 4
#define Ss 1024
#define Dd 1024
#define Ff 2048
#define Hh 8
#define DHd 128
#define Mm (Bb * Ss)   // 4096 rows
#define EPSf 1e-5f
#define LDQ 4096       // combined QKVG row stride

typedef __attribute__((ext_vector_type(8))) short short8v;
typedef __attribute__((ext_vector_type(4))) float f32x4;
typedef __attribute__((ext_vector_type(4))) unsigned int u32x4;

__device__ __forceinline__ float swish_f(float x) { return x / (1.f + expf(-x)); }
__device__ __forceinline__ float gelu_f(float x) {
  return 0.5f * x * (1.f + tanhf(0.7978845608028654f * (x + 0.044715f * x * x * x)));
}
__device__ __forceinline__ unsigned short f2bfu(float f) {
  __hip_bfloat16 h = __float2bfloat16(f);
  return __builtin_bit_cast(unsigned short, h);
}
__device__ __forceinline__ float bfu2f(unsigned short u) {
  unsigned v = ((unsigned)u) << 16;
  return __builtin_bit_cast(float, v);
}
__device__ __forceinline__ void gl_lds16(const void* g, void* l) {
  __builtin_amdgcn_global_load_lds((__attribute__((address_space(1))) void*)g,
                                   (__attribute__((address_space(3))) void*)l, 16, 0, 0);
}
__device__ __forceinline__ f32x4 mfma16(short8v a, short8v b, f32x4 c) {
  return __builtin_amdgcn_mfma_f32_16x16x32_bf16(a, b, c, 0, 0, 0);
}

// ---------------- LayerNorm fp32 -> bf16 (standalone, used for FFN LN) ----------------
__global__ __launch_bounds__(256) void ln_bf16_kernel(const float* __restrict__ x,
                                                      short* __restrict__ outb,
                                                      const float* __restrict__ sc,
                                                      const float* __restrict__ bi) {
  const int row = blockIdx.x;
  const int t = threadIdx.x;
  const float4 v = *(const float4*)(x + (size_t)row * Dd + t * 4);
  float s = v.x + v.y + v.z + v.w;
  float s2 = v.x * v.x + v.y * v.y + v.z * v.z + v.w * v.w;
#pragma unroll
  for (int o = 32; o > 0; o >>= 1) { s += __shfl_down(s, o); s2 += __shfl_down(s2, o); }
  __shared__ float ps[4], ps2[4];
  if ((t & 63) == 0) { ps[t >> 6] = s; ps2[t >> 6] = s2; }
  __syncthreads();
  s = ps[0] + ps[1] + ps[2] + ps[3];
  s2 = ps2[0] + ps2[1] + ps2[2] + ps2[3];
  const float mu = s * (1.f / Dd);
  const float var = s2 * (1.f / Dd) - mu * mu;
  const float rstd = rsqrtf(var + EPSf);
  const float4 g = *(const float4*)(sc + t * 4);
  const float4 b = *(const float4*)(bi + t * 4);
  const float o0 = (v.x - mu) * rstd * g.x + b.x;
  const float o1 = (v.y - mu) * rstd * g.y + b.y;
  const float o2 = (v.z - mu) * rstd * g.z + b.z;
  const float o3 = (v.w - mu) * rstd * g.w + b.w;
  unsigned p0 = (unsigned)f2bfu(o0) | ((unsigned)f2bfu(o1) << 16);
  unsigned p1 = (unsigned)f2bfu(o2) | ((unsigned)f2bfu(o3) << 16);
  uint2 pk; pk.x = p0; pk.y = p1;
  *(uint2*)(outb + (size_t)row * Dd + t * 4) = pk;
}

// ---------------- RoPE tables ----------------
__global__ void rope_table_kernel(float* __restrict__ ct, float* __restrict__ st) {
  const int i = blockIdx.x * 256 + threadIdx.x;  // < Ss*64
  const int s = i >> 6, f = i & 63;
  const float inv = powf(10000.f, -(float)f / 64.f);
  const float a = (float)s * inv;
  ct[i] = cosf(a);
  st[i] = sinf(a);
}

// ---------------- merged weight transpose + LN(Acur): one dispatch (13312 blocks) --------
__global__ __launch_bounds__(256) void wtrans_ln_kernel(
    const float* __restrict__ Wq, const float* __restrict__ Wk,
    const float* __restrict__ Wv, const float* __restrict__ Wg,
    const float* __restrict__ Wo, const float* __restrict__ W1,
    const float* __restrict__ W2,
    short* __restrict__ Wqkvgt, short* __restrict__ Wot,
    short* __restrict__ W1t, short* __restrict__ W2t,
    const float* __restrict__ x, short* __restrict__ outb,
    const float* __restrict__ sc, const float* __restrict__ bi) {
  __shared__ float tile[32][33];
  __shared__ float ps[4], ps2[4];
  const int t = threadIdx.x;
  const int blk = blockIdx.x;
  if (blk >= 9216) {
    const int row = blk - 9216;
    const float4 v = *(const float4*)(x + (size_t)row * Dd + t * 4);
    float s = v.x + v.y + v.z + v.w;
    float s2 = v.x * v.x + v.y * v.y + v.z * v.z + v.w * v.w;
#pragma unroll
    for (int o = 32; o > 0; o >>= 1) { s += __shfl_down(s, o); s2 += __shfl_down(s2, o); }
    if ((t & 63) == 0) { ps[t >> 6] = s; ps2[t >> 6] = s2; }
    __syncthreads();
    s = ps[0] + ps[1] + ps[2] + ps[3];
    s2 = ps2[0] + ps2[1] + ps2[2] + ps2[3];
    const float mu = s * (1.f / Dd);
    const float var = s2 * (1.f / Dd) - mu * mu;
    const float rstd = rsqrtf(var + EPSf);
    const float4 g = *(const float4*)(sc + t * 4);
    const float4 b = *(const float4*)(bi + t * 4);
    const float o0 = (v.x - mu) * rstd * g.x + b.x;
    const float o1 = (v.y - mu) * rstd * g.y + b.y;
    const float o2 = (v.z - mu) * rstd * g.z + b.z;
    const float o3 = (v.w - mu) * rstd * g.w + b.w;
    unsigned p0 = (unsigned)f2bfu(o0) | ((unsigned)f2bfu(o1) << 16);
    unsigned p1 = (unsigned)f2bfu(o2) | ((unsigned)f2bfu(o3) << 16);
    uint2 pk; pk.x = p0; pk.y = p1;
    *(uint2*)(outb + (size_t)row * Dd + t * 4) = pk;
    return;
  }
  const int tc = t & 31, tr8 = t >> 5;
  const float* src; short* dst; int K, N, n0, k0, nl;
  if (blk < 4096) {
    const int bx = blk & 127, ky = blk >> 7;
    n0 = bx * 32; k0 = ky * 32;
    const int which = n0 >> 10;
    src = (which == 0) ? Wq : (which == 1) ? Wk : (which == 2) ? Wv : Wg;
    nl = n0 & 1023; N = 1024; K = 1024; dst = Wqkvgt;
  } else if (blk < 5120) {
    const int b2 = blk - 4096;
    n0 = (b2 & 31) * 32; k0 = (b2 >> 5) * 32; nl = n0;
    src = Wo; N = 1024; K = 1024; dst = Wot;
  } else if (blk < 7168) {
    const int b2 = blk - 5120;
    n0 = (b2 & 63) * 32; k0 = (b2 >> 6) * 32; nl = n0;
    src = W1; N = 2048; K = 1024; dst = W1t;
  } else {
    const int b2 = blk - 7168;
    n0 = (b2 & 31) * 32; k0 = (b2 >> 5) * 32; nl = n0;
    src = W2; N = 1024; K = 2048; dst = W2t;
  }
#pragma unroll
  for (int i = 0; i < 4; ++i) {
    const int r = tr8 + i * 8;
    tile[r][tc] = src[(size_t)(k0 + r) * N + nl + tc];
  }
  __syncthreads();
#pragma unroll
  for (int i = 0; i < 4; ++i) {
    const int r = tr8 + i * 8;
    dst[(size_t)(n0 + r) * K + k0 + tc] = (short)f2bfu(tile[tc][r]);
  }
}

// ---------------- bf16 MFMA GEMM v10b: 256x256 8-phase, BK=32, 64 KB LDS (2 blocks/CU) ----
// Same phase/stage/vmcnt algebra as v10 scaled to 1-load stages: vmcnt(2) steady, 0 at tail.
// Epilogues: V^T via two 64KB LDS passes; fused RoPE on Q/K (register-only).
template <int EPI>
__global__ __launch_bounds__(512, 2) void gemm10(const short* __restrict__ A,
                                                 const short* __restrict__ Bt,
                                                 float* __restrict__ Cf,
                                                 short* __restrict__ Cb,
                                                 const float* __restrict__ Res,
                                                 short* __restrict__ Vt,
                                                 const float* __restrict__ ct,
                                                 const float* __restrict__ st,
                                                 int N, int K, int ldc) {
  __shared__ __align__(16) short SM[32768];   // 64 KB: As = SM[0..16383], Bs = SM[16384..]
  const int t = threadIdx.x;
  const int w = t >> 6, l = t & 63;
  const int lq = l >> 4, lr = l & 15;
  const int wr = w >> 2, wc = w & 3;
  const int bhalf = wc >> 1, brow0 = (wc & 1) * 64;
  const int nwg = gridDim.x * gridDim.y;
  const int bid0 = blockIdx.x + blockIdx.y * gridDim.x;
  const int lgid = (bid0 & 7) * (nwg >> 3) + (bid0 >> 3);
  const int bx = lgid % gridDim.x, by = lgid / gridDim.x;
  const int row0 = by * 256, col0 = bx * 256;
  const int NT = K >> 5;   // BK = 32

  f32x4 acc[8][4] = {};
  short8v a[4], b[4];

  auto stageA = [&](int kt, int hf) {
    const int db = kt & 1;
    short* dstb = SM + (db * 2 + hf) * 4096;
    const int row = t >> 2, slot = t & 3;
    gl_lds16(A + (size_t)(row0 + hf * 128 + row) * K + kt * 32 +
                 ((slot ^ ((row >> 1) & 3)) << 3),
             dstb + t * 8);
  };
  auto stageB = [&](int kt, int hf) {
    const int db = kt & 1;
    short* dstb = SM + 16384 + (db * 2 + hf) * 4096;
    const int row = t >> 2, slot = t & 3;
    gl_lds16(Bt + (size_t)(col0 + hf * 128 + row) * K + kt * 32 +
                 ((slot ^ ((row >> 1) & 3)) << 3),
             dstb + t * 8);
  };
  auto rdA = [&](int db, int m) -> short8v {
    const int row = m * 16 + lr;
    return *(const short8v*)(SM + (db * 2 + wr) * 4096 + row * 32 +
                             ((lq ^ ((row >> 1) & 3)) << 3));
  };
  auto rdB = [&](int db, int n) -> short8v {
    const int row = brow0 + n * 16 + lr;
    return *(const short8v*)(SM + 16384 + (db * 2 + bhalf) * 4096 + row * 32 +
                             ((lq ^ ((row >> 1) & 3)) << 3));
  };

  // prologue: A(0) both halves, B(0) both halves, B(1) both halves (6 loads);
  // drain A(0)+B(0), leave B(1)'s 2 flying.
  stageA(0, 0); stageA(0, 1); stageB(0, 0); stageB(0, 1);
  stageB(1, 0); stageB(1, 1);
  asm volatile("s_waitcnt vmcnt(2)" ::: "memory");
  asm volatile("s_barrier" ::: "memory");

  for (int kt = 0; kt < NT; ++kt) {
    const int db = kt & 1;
    // ---- phA: read a(m0-3)+b(n0-1); stage A0(kt+1); MFMA 8 ----
#pragma unroll
    for (int m = 0; m < 4; ++m) a[m] = rdA(db, m);
#pragma unroll
    for (int n = 0; n < 2; ++n) b[n] = rdB(db, n);
    if (kt + 1 < NT) stageA(kt + 1, 0);
    __builtin_amdgcn_s_setprio(1);
#pragma unroll
    for (int m = 0; m < 4; ++m)
#pragma unroll
      for (int n = 0; n < 2; ++n) acc[m][n] = mfma16(a[m], b[n], acc[m][n]);
    __builtin_amdgcn_s_setprio(0);
    asm volatile("s_barrier" ::: "memory");
    // ---- phB: read b(n2-3); stage A1(kt+1); MFMA 8 ----
#pragma unroll
    for (int n = 2; n < 4; ++n) b[n] = rdB(db, n);
    if (kt + 1 < NT) stageA(kt + 1, 1);
    __builtin_amdgcn_s_setprio(1);
#pragma unroll
    for (int m = 0; m < 4; ++m)
#pragma unroll
      for (int n = 2; n < 4; ++n) acc[m][n] = mfma16(a[m], b[n], acc[m][n]);
    __builtin_amdgcn_s_setprio(0);
    asm volatile("s_barrier" ::: "memory");
    // ---- phC: read a(m4-7); stage B0(kt+2); MFMA 8 ----
#pragma unroll
    for (int m = 0; m < 4; ++m) a[m] = rdA(db, m + 4);
    if (kt + 2 < NT) stageB(kt + 2, 0);
    __builtin_amdgcn_s_setprio(1);
#pragma unroll
    for (int m = 0; m < 4; ++m)
#pragma unroll
      for (int n = 0; n < 2; ++n) acc[m + 4][n] = mfma16(a[m], b[n], acc[m + 4][n]);
    __builtin_amdgcn_s_setprio(0);
    asm volatile("s_barrier" ::: "memory");
    // ---- phD: stage B1(kt+2); MFMA 8; counted vmcnt; barrier ----
    if (kt + 2 < NT) stageB(kt + 2, 1);
    __builtin_amdgcn_s_setprio(1);
#pragma unroll
    for (int m = 0; m < 4; ++m)
#pragma unroll
      for (int n = 2; n < 4; ++n) acc[m + 4][n] = mfma16(a[m], b[n], acc[m + 4][n]);
    __builtin_amdgcn_s_setprio(0);
    if (kt + 2 < NT) { asm volatile("s_waitcnt vmcnt(2)" ::: "memory"); }
    else             { asm volatile("s_waitcnt vmcnt(0)" ::: "memory"); }
    asm volatile("s_barrier" ::: "memory");
  }

  if (EPI == 0 && col0 >= 2048 && col0 < 3072) {
    // V-block: transpose through (dead) 64KB LDS in TWO passes of 128 d-cols each.
    const int bI = row0 >> 10;
    const int s0g = row0 & 1023;
#pragma unroll
    for (int p = 0; p < 2; ++p) {
      if ((wc >> 1) == p) {
#pragma unroll
        for (int m = 0; m < 8; ++m)
#pragma unroll
          for (int n = 0; n < 4; ++n)
#pragma unroll
            for (int r = 0; r < 4; ++r) {
              const int ls = wr * 128 + m * 16 + lq * 4 + r;       // local s 0..255
              const int ld = (wc & 1) * 64 + n * 16 + lr;          // local d 0..127
              SM[ld * 256 + ((((ls >> 3) ^ (ld & 31)) << 3) | (ls & 7))] =
                  (short)f2bfu(acc[m][n][r]);
            }
      }
      __syncthreads();
#pragma unroll 4
      for (int rr = 0; rr < 16; ++rr) {
        const int dl = w * 16 + rr;                                // 0..127
        const int gcol = (col0 - 2048) + p * 128 + dl;
        const int hh = gcol >> 7, dh = gcol & 127;
        const int s0 = l * 4;
        const unsigned short e0 =
            (unsigned short)SM[dl * 256 + ((((s0 + 0) >> 3) ^ (dl & 31)) << 3 | ((s0 + 0) & 7))];
        const unsigned short e1 =
            (unsigned short)SM[dl * 256 + ((((s0 + 1) >> 3) ^ (dl & 31)) << 3 | ((s0 + 1) & 7))];
        const unsigned short e2 =
            (unsigned short)SM[dl * 256 + ((((s0 + 2) >> 3) ^ (dl & 31)) << 3 | ((s0 + 2) & 7))];
        const unsigned short e3 =
            (unsigned short)SM[dl * 256 + ((((s0 + 3) >> 3) ^ (dl & 31)) << 3 | ((s0 + 3) & 7))];
        uint2 pk;
        pk.x = (unsigned)e0 | ((unsigned)e1 << 16);
        pk.y = (unsigned)e2 | ((unsigned)e3 << 16);
        *(uint2*)(Vt + ((size_t)((bI * 8 + hh) * 128 + dh)) * Ss + s0g + l * 4) = pk;
      }
      __syncthreads();
    }
    return;
  }

  if (EPI == 0 && col0 < 2048) {
    // Q/K-block: fused RoPE in-register (pair element lives in lane l^1, same (m,n,r)).
    const bool isQ = (col0 < 1024);
    const int odd = lr & 1;
#pragma unroll
    for (int m = 0; m < 8; ++m) {
#pragma unroll
      for (int n = 0; n < 4; ++n) {
#pragma unroll
        for (int r = 0; r < 4; ++r) {
          const int row = row0 + wr * 128 + m * 16 + lq * 4 + r;
          const int col = col0 + wc * 64 + n * 16 + lr;
          const float v = acc[m][n][r];
          const float px = __shfl_xor(v, 1);
          const int spos = row & (Ss - 1);
          const int f = (col >> 1) & 63;
          const float cc = ct[(spos << 6) + f];
          const float sn = st[(spos << 6) + f];
          float ov;
          if (isQ) ov = v * cc + (odd ? px * sn : -px * sn);
          else     ov = v * cc + (odd ? -px * sn : px * sn);
          Cb[(size_t)row * ldc + col] = (short)f2bfu(ov);
        }
      }
    }
    return;
  }

#pragma unroll
  for (int m = 0; m < 8; ++m) {
#pragma unroll
    for (int n = 0; n < 4; ++n) {
#pragma unroll
      for (int r = 0; r < 4; ++r) {
        const int row = row0 + wr * 128 + m * 16 + lq * 4 + r;
        const int col = col0 + wc * 64 + n * 16 + lr;
        const size_t o = (size_t)row * ldc + col;
        float v = acc[m][n][r];
        if (EPI == 0) Cb[o] = (short)f2bfu(v);
        else if (EPI == 1) Cf[o] = v + Res[o];
        else Cb[o] = (short)f2bfu(gelu_f(v));
      }
    }
  }
}

// ---------------- bf16 MFMA GEMM v11: 256x128 2-phase/K-tile, ring-3 LDS, vmcnt(6) --------
template <int EPI>
__global__ __launch_bounds__(512) void gemm11(const short* __restrict__ A,
                                              const short* __restrict__ Bt,
                                              float* __restrict__ Cf,
                                              short* __restrict__ Cb,
                                              const float* __restrict__ Res,
                                              int K, int lda, int ldb, int ldc, int nxt) {
  __shared__ __align__(16) short As[3][256 * 64];  // 96 KB ring-3
  __shared__ __align__(16) short Bs[3][128 * 64];  // 48 KB ring-3
  const int t = threadIdx.x;
  const int w = t >> 6, l = t & 63;
  const int lq = l >> 4, lr = l & 15;
  const int wr = w >> 2, wc = w & 3;
  const int nwg = gridDim.x;
  const int lgid = (blockIdx.x & 7) * (nwg >> 3) + (blockIdx.x >> 3);
  const int mt = lgid / nxt, nt_ = lgid % nxt;
  const int row0 = mt * 256, col0 = nt_ * 128;
  const int NT = K >> 6;
  f32x4 acc[8][2] = {};
  short8v a[4][2], b[2][2];

  auto stageA = [&](int kt, int hf) {
    const int s = kt % 3;
#pragma unroll
    for (int i = 0; i < 2; ++i) {
      const int c = t + i * 512;
      const int row = c >> 3, slot = c & 7;
      gl_lds16(A + (size_t)(row0 + hf * 128 + row) * lda + kt * 64 + ((slot ^ (row & 7)) << 3),
               &As[s][hf * 8192 + c * 8]);
    }
  };
  auto stageB = [&](int kt) {
    const int s = kt % 3;
#pragma unroll
    for (int i = 0; i < 2; ++i) {
      const int c = t + i * 512;
      const int row = c >> 3, slot = c & 7;
      gl_lds16(Bt + (size_t)(col0 + row) * ldb + kt * 64 + ((slot ^ (row & 7)) << 3),
               &Bs[s][c * 8]);
    }
  };
  auto rdA = [&](int s, int m, int ks) -> short8v {
    const int row = wr * 128 + m * 16 + lr;
    return *(const short8v*)&As[s][row * 64 + (((ks << 2) + lq) ^ (row & 7)) * 8];
  };
  auto rdB = [&](int s, int n, int ks) -> short8v {
    const int row = wc * 32 + n * 16 + lr;
    return *(const short8v*)&Bs[s][row * 64 + (((ks << 2) + lq) ^ (row & 7)) * 8];
  };

  stageA(0, 0); stageA(0, 1); stageB(0);
  stageA(1, 0); stageA(1, 1); stageB(1);
  asm volatile("s_waitcnt vmcnt(6)" ::: "memory");
  asm volatile("s_barrier" ::: "memory");

  for (int kt = 0; kt < NT; ++kt) {
    const int s = kt % 3;
#pragma unroll
    for (int m = 0; m < 4; ++m) { a[m][0] = rdA(s, m, 0); a[m][1] = rdA(s, m, 1); }
#pragma unroll
    for (int n = 0; n < 2; ++n) { b[n][0] = rdB(s, n, 0); b[n][1] = rdB(s, n, 1); }
    if (kt + 2 < NT) stageA(kt + 2, 0);
    __builtin_amdgcn_s_setprio(1);
#pragma unroll
    for (int m = 0; m < 4; ++m)
#pragma unroll
      for (int n = 0; n < 2; ++n) {
        acc[m][n] = mfma16(a[m][0], b[n][0], acc[m][n]);
        acc[m][n] = mfma16(a[m][1], b[n][1], acc[m][n]);
      }
    __builtin_amdgcn_s_setprio(0);
    asm volatile("s_barrier" ::: "memory");
#pragma unroll
    for (int m = 0; m < 4; ++m) { a[m][0] = rdA(s, m + 4, 0); a[m][1] = rdA(s, m + 4, 1); }
    if (kt + 2 < NT) { stageA(kt + 2, 1); stageB(kt + 2); }
    __builtin_amdgcn_s_setprio(1);
#pragma unroll
    for (int m = 0; m < 4; ++m)
#pragma unroll
      for (int n = 0; n < 2; ++n) {
        acc[m + 4][n] = mfma16(a[m][0], b[n][0], acc[m + 4][n]);
        acc[m + 4][n] = mfma16(a[m][1], b[n][1], acc[m + 4][n]);
      }
    __builtin_amdgcn_s_setprio(0);
    if (kt + 2 < NT) { asm volatile("s_waitcnt vmcnt(6)" ::: "memory"); }
    else             { asm volatile("s_waitcnt vmcnt(0)" ::: "memory"); }
    asm volatile("s_barrier" ::: "memory");
  }

#pragma unroll
  for (int m = 0; m < 8; ++m) {
#pragma unroll
    for (int n = 0; n < 2; ++n) {
#pragma unroll
      for (int r = 0; r < 4; ++r) {
        const int row = row0 + wr * 128 + m * 16 + lq * 4 + r;
        const int col = col0 + wc * 32 + n * 16 + lr;
        const size_t o = (size_t)row * ldc + col;
        float v = acc[m][n][r];
        if (EPI == 0) Cb[o] = (short)f2bfu(v);
        else if (EPI == 1) Cf[o] = v + Res[o];
        else Cb[o] = (short)f2bfu(gelu_f(v));
      }
    }
  }
}

// ---------------- bf16 MFMA GEMM v12: 128x128 2-phase/K-tile, ring-3 LDS, vmcnt(4) --------
template <int EPI>
__global__ __launch_bounds__(512) void gemm12(const short* __restrict__ A,
                                              const short* __restrict__ Bt,
                                              float* __restrict__ Cf,
                                              short* __restrict__ Cb,
                                              const float* __restrict__ Res,
                                              int K, int lda, int ldb, int ldc, int nxt) {
  __shared__ __align__(16) short As[3][128 * 64];  // 48 KB ring-3
  __shared__ __align__(16) short Bs[3][128 * 64];  // 48 KB ring-3
  const int t = threadIdx.x;
  const int w = t >> 6, l = t & 63;
  const int lq = l >> 4, lr = l & 15;
  const int wr = w >> 2, wc = w & 3;
  const int nwg = gridDim.x;
  const int lgid = (blockIdx.x & 7) * (nwg >> 3) + (blockIdx.x >> 3);
  const int mt = lgid / nxt, nt_ = lgid % nxt;
  const int row0 = mt * 128, col0 = nt_ * 128;
  const int NT = K >> 6;
  f32x4 acc[4][2] = {};
  short8v a[4][2], b[2][2];

  auto stageA = [&](int kt) {
    const int s = kt % 3;
#pragma unroll
    for (int i = 0; i < 2; ++i) {
      const int c = t + i * 512;
      const int row = c >> 3, slot = c & 7;
      gl_lds16(A + (size_t)(row0 + row) * lda + kt * 64 + ((slot ^ (row & 7)) << 3),
               &As[s][c * 8]);
    }
  };
  auto stageB = [&](int kt) {
    const int s = kt % 3;
#pragma unroll
    for (int i = 0; i < 2; ++i) {
      const int c = t + i * 512;
      const int row = c >> 3, slot = c & 7;
      gl_lds16(Bt + (size_t)(col0 + row) * ldb + kt * 64 + ((slot ^ (row & 7)) << 3),
               &Bs[s][c * 8]);
    }
  };
  auto rdA = [&](int s, int m, int ks) -> short8v {
    const int row = wr * 64 + m * 16 + lr;
    return *(const short8v*)&As[s][row * 64 + (((ks << 2) + lq) ^ (row & 7)) * 8];
  };
  auto rdB = [&](int s, int n, int ks) -> short8v {
    const int row = wc * 32 + n * 16 + lr;
    return *(const short8v*)&Bs[s][row * 64 + (((ks << 2) + lq) ^ (row & 7)) * 8];
  };

  stageA(0); stageB(0);
  stageA(1); stageB(1);
  asm volatile("s_waitcnt vmcnt(4)" ::: "memory");
  asm volatile("s_barrier" ::: "memory");

  for (int kt = 0; kt < NT; ++kt) {
    const int s = kt % 3;
#pragma unroll
    for (int m = 0; m < 4; ++m) { a[m][0] = rdA(s, m, 0); a[m][1] = rdA(s, m, 1); }
#pragma unroll
    for (int n = 0; n < 2; ++n) { b[n][0] = rdB(s, n, 0); b[n][1] = rdB(s, n, 1); }
    if (kt + 2 < NT) stageA(kt + 2);
    __builtin_amdgcn_s_setprio(1);
#pragma unroll
    for (int m = 0; m < 2; ++m)
#pragma unroll
      for (int n = 0; n < 2; ++n) {
        acc[m][n] = mfma16(a[m][0], b[n][0], acc[m][n]);
        acc[m][n] = mfma16(a[m][1], b[n][1], acc[m][n]);
      }
    __builtin_amdgcn_s_setprio(0);
    asm volatile("s_barrier" ::: "memory");
    if (kt + 2 < NT) stageB(kt + 2);
    __builtin_amdgcn_s_setprio(1);
#pragma unroll
    for (int m = 2; m < 4; ++m)
#pragma unroll
      for (int n = 0; n < 2; ++n) {
        acc[m][n] = mfma16(a[m][0], b[n][0], acc[m][n]);
        acc[m][n] = mfma16(a[m][1], b[n][1], acc[m][n]);
      }
    __builtin_amdgcn_s_setprio(0);
    if (kt + 2 < NT) { asm volatile("s_waitcnt vmcnt(4)" ::: "memory"); }
    else             { asm volatile("s_waitcnt vmcnt(0)" ::: "memory"); }
    asm volatile("s_barrier" ::: "memory");
  }

#pragma unroll
  for (int m = 0; m < 4; ++m) {
#pragma unroll
    for (int n = 0; n < 2; ++n) {
#pragma unroll
      for (int r = 0; r < 4; ++r) {
        const int row = row0 + wr * 64 + m * 16 + lq * 4 + r;
        const int col = col0 + wc * 32 + n * 16 + lr;
        const size_t o = (size_t)row * ldc + col;
        float v = acc[m][n][r];
        if (EPI == 0) Cb[o] = (short)f2bfu(v);
        else if (EPI == 1) Cf[o] = v + Res[o];
        else Cb[o] = (short)f2bfu(gelu_f(v));
      }
    }
  }
}

// ---------------- Retention v5: fused GN+gate, paired q-blocks (qb,15-qb), QBLK=64 --------
__global__ __launch_bounds__(256) void ret5_kernel(const short* __restrict__ QKVGb,
                                                   const short* __restrict__ Vt,
                                                   short* __restrict__ Gb,
                                                   const float* __restrict__ gs,
                                                   const float* __restrict__ gb) {
  __shared__ __align__(16) short Ks[2][64 * 128];
  __shared__ __align__(16) short Vs[2][128 * 64];
  const int t = threadIdx.x, w = t >> 6, l = t & 63;
  const int lq = l >> 4, lr = l & 15;
  const int u = blockIdx.x;                     // 0..255
  const int lgid = (u & 7) * 32 + (u >> 3);     // XCD-contiguous
  const int bh = lgid >> 3, pr = lgid & 7;
  const int b = bh >> 3, h = bh & 7;
  const float lstep = (logf(1.f / 512.f) - logf(1.f / 32.f)) * (1.f / 7.f);
  const float gamma = 1.f - expf(logf(1.f / 32.f) + (float)h * lstep);
  const float l2g = logf(gamma) * 1.44269504f;
  const short* Qp = QKVGb;
  const short* Kp = QKVGb + 1024;

  float cmf[4], csr[4];
#pragma unroll
  for (int mf = 0; mf < 4; ++mf) cmf[mf] = exp2f(l2g * (float)(-16 * mf));
#pragma unroll
  for (int r = 0; r < 4; ++r) csr[r] = exp2f(l2g * (float)(63 - 4 * lq - r));
  float gsv[8], gbv[8];
#pragma unroll
  for (int nd = 0; nd < 8; ++nd) {
    gsv[nd] = gs[h * DHd + nd * 16 + lr];
    gbv[nd] = gb[h * DHd + nd * 16 + lr];
  }
  const int sb = ((lq & 1) * 2) * 16 + lr;

  auto stageKV = [&](int m0, int buf) {
#pragma unroll
    for (int i = 0; i < 4; ++i) {
      const int c = (w * 4 + i) * 64 + l;
      const int row = c >> 4, slot = c & 15;
      gl_lds16(Kp + (size_t)(b * Ss + m0 + row) * LDQ + h * DHd + ((slot ^ (row & 7)) * 8),
               &Ks[buf][(w * 4 + i) * 512]);
    }
#pragma unroll
    for (int i = 0; i < 4; ++i) {
      const int c = (w * 4 + i) * 64 + l;
      const int row = c >> 3, slot = c & 7;
      gl_lds16(Vt + (size_t)(bh * DHd + row) * Ss + m0 + ((slot ^ (row & 7)) * 8),
               &Vs[buf][(w * 4 + i) * 512]);
    }
  };

  for (int pass = 0; pass < 2; ++pass) {
    const int qb = pass ? (15 - pr) : pr;
    const int q0 = qb * 64;
    const int nt = qb + 1;
    short8v qf[4];
#pragma unroll
    for (int ks = 0; ks < 4; ++ks)
      qf[ks] = *(const short8v*)(Qp + (size_t)(b * Ss + q0 + w * 16 + lr) * LDQ +
                                 h * DHd + ks * 32 + lq * 8);
    f32x4 yacc[8] = {};
    stageKV(0, 0);
    __syncthreads();
    int cur = 0;
    for (int tt = 0; tt < nt; ++tt) {
      const int m0 = tt * 64;
      if (tt + 1 < nt) stageKV((tt + 1) * 64, cur ^ 1);

      f32x4 st[4] = {};
      __builtin_amdgcn_s_setprio(1);
#pragma unroll
      for (int mf = 0; mf < 4; ++mf) {
        const int row = mf * 16 + lr;
#pragma unroll
        for (int ks = 0; ks < 4; ++ks) {
          short8v kf = *(const short8v*)&Ks[cur][row * 128 + (((4 * ks + lq) ^ (row & 7)) * 8)];
          st[mf] = mfma16(kf, qf[ks], st[mf]);
        }
      }
      __builtin_amdgcn_s_setprio(0);
      const int qg = q0 + w * 16 + lr;
      const float rs = exp2f(l2g * (float)(qg - m0 - 63));
#pragma unroll
      for (int mf = 0; mf < 4; ++mf)
#pragma unroll
        for (int r = 0; r < 4; ++r) {
          const int kvg = m0 + mf * 16 + lq * 4 + r;
          const float wgt = (qg >= kvg) ? rs * cmf[mf] * csr[r] : 0.f;
          st[mf][r] *= wgt;
        }
      unsigned pk[4][2];
#pragma unroll
      for (int mf = 0; mf < 4; ++mf)
#pragma unroll
        for (int p = 0; p < 2; ++p)
          pk[mf][p] = (unsigned)f2bfu(st[mf][2 * p]) |
                      ((unsigned)f2bfu(st[mf][2 * p + 1]) << 16);
      short8v afr[2];
#pragma unroll
      for (int ks2 = 0; ks2 < 2; ++ks2) {
        u32x4 wd;
#pragma unroll
        for (int wj = 0; wj < 4; ++wj) {
          const int src = sb + (wj >> 1) * 16;
          const unsigned v0 = __shfl(pk[2 * ks2 + 0][wj & 1], src);
          const unsigned v1 = __shfl(pk[2 * ks2 + 1][wj & 1], src);
          wd[wj] = (lq >= 2) ? v1 : v0;
        }
        afr[ks2] = __builtin_bit_cast(short8v, wd);
      }
      __builtin_amdgcn_s_setprio(1);
#pragma unroll
      for (int nd = 0; nd < 8; ++nd) {
        const int row = nd * 16 + lr;
#pragma unroll
        for (int ks2 = 0; ks2 < 2; ++ks2) {
          short8v vf = *(const short8v*)&Vs[cur][row * 64 + (((4 * ks2 + lq) ^ (row & 7)) * 8)];
          yacc[nd] = mfma16(afr[ks2], vf, yacc[nd]);
        }
      }
      __builtin_amdgcn_s_setprio(0);
      __syncthreads();
      cur ^= 1;
    }
    // fused GroupNorm + gate epilogue
#pragma unroll
    for (int r = 0; r < 4; ++r) {
      float s1 = 0.f, s2 = 0.f;
#pragma unroll
      for (int nd = 0; nd < 8; ++nd) { const float v = yacc[nd][r]; s1 += v; s2 += v * v; }
#pragma unroll
      for (int msk = 1; msk < 16; msk <<= 1) {
        s1 += __shfl_xor(s1, msk);
        s2 += __shfl_xor(s2, msk);
      }
      const float mu = s1 * (1.f / 128.f);
      const float rstd = rsqrtf(s2 * (1.f / 128.f) - mu * mu + EPSf);
      const int q = q0 + w * 16 + lq * 4 + r;
      const size_t gbase = (size_t)(b * Ss + q) * LDQ + 3072 + h * DHd;
      const size_t obase = (size_t)(b * Ss + q) * Dd + h * DHd;
#pragma unroll
      for (int nd = 0; nd < 8; ++nd) {
        const int d = nd * 16 + lr;
        const float yv = (yacc[nd][r] - mu) * rstd * gsv[nd] + gbv[nd];
        const float gvx = bfu2f((unsigned short)QKVGb[gbase + d]);
        Gb[obase + d] = (short)f2bfu(swish_f(gvx) * yv);
      }
    }
  }
}

extern "C" void kernel_launch(void* const* d_in, const int* in_sizes, int n_in,
                              void* d_out, int out_size, void* d_ws, size_t ws_size,
                              hipStream_t stream) {
  const float* X = (const float*)d_in[0];
  const float* Wq = (const float*)d_in[1];
  const float* Wk = (const float*)d_in[2];
  const float* Wv = (const float*)d_in[3];
  const float* Wg = (const float*)d_in[4];
  const float* Wo = (const float*)d_in[5];
  const float* W1 = (const float*)d_in[6];
  const float* W2 = (const float*)d_in[7];
  const float* lns = (const float*)d_in[8];
  const float* lnb = (const float*)d_in[9];
  const float* gns = (const float*)d_in[10];
  const float* gnb = (const float*)d_in[11];
  float* out = (float*)d_out;

  char* W = (char*)d_ws;
  const size_t MB = 1u << 20;
  float* Abuf  = (float*)(W);             // 16 MB fp32
  short* Xnb   = (short*)(W + 16 * MB);   // 8 MB bf16
  short* QKVGb = (short*)(W + 24 * MB);   // 32 MB bf16 [4096][4096]; Hb aliases first 16 MB
  short* Vtb   = (short*)(W + 88 * MB);   // 8 MB bf16
  short* Gb    = (short*)(W + 96 * MB);   // 8 MB bf16
  short* Wqkvgt= (short*)(W + 104 * MB);  // 8 MB
  short* Wot   = (short*)(W + 112 * MB);  // 2 MB
  short* W1t   = (short*)(W + 114 * MB);  // 4 MB
  short* W2t   = (short*)(W + 118 * MB);  // 4 MB
  float* ct    = (float*)(W + 122 * MB);  // 256 KB
  float* st    = ct + Ss * 64;            // 256 KB
  short* Hb = QKVGb;  // FFN hidden 4096x2048 bf16 (16 MB)

  rope_table_kernel<<<(Ss * 64) / 256, 256, 0, stream>>>(ct, st);

  for (int l = 0; l < LAYERS; ++l) {
    const size_t DD = (size_t)Dd * Dd;
    const float* Acur = (l == 0) ? X : Abuf;  // residual stream input for this layer
    // merged: weight transposes + LN(Acur) in one dispatch
    wtrans_ln_kernel<<<13312, 256, 0, stream>>>(Wq + l * DD, Wk + l * DD, Wv + l * DD,
                                                Wg + l * DD, Wo + l * DD,
                                                W1 + (size_t)l * Dd * Ff,
                                                W2 + (size_t)l * Ff * Dd,
                                                Wqkvgt, Wot, W1t, W2t,
                                                Acur, Xnb, lns, lnb);
    // fused QKVG projection (8-phase 256x256, BK=32, 2 blocks/CU) + V^T + fused RoPE
    gemm10<0><<<dim3(16, 16), 512, 0, stream>>>(Xnb, Wqkvgt, nullptr, QKVGb,
                                                nullptr, Vtb, ct, st, 4096, Dd, LDQ);
    // retention + fused GN/gate -> Gb (bf16)
    ret5_kernel<<<256, 256, 0, stream>>>(QKVGb, Vtb, Gb,
                                         gns + (size_t)l * Dd, gnb + (size_t)l * Dd);
    // A = (Gb @ Wo) + Acur
    gemm12<1><<<256, 512, 0, stream>>>(Gb, Wot, Abuf, nullptr, Acur,
                                       Dd, Dd, Dd, Dd, 8);
    // FFN
    ln_bf16_kernel<<<Mm, 256, 0, stream>>>(Abuf, Xnb, lns, lnb);
    gemm11<2><<<256, 512, 0, stream>>>(Xnb, W1t, nullptr, Hb, nullptr,
                                       Dd, Dd, Dd, Ff, 16);
    float* dst = (l == LAYERS - 1) ? out : Abuf;
    gemm12<1><<<256, 512, 0, stream>>>(Hb, W2t, dst, nullptr, Abuf,
                                       Ff, Ff, Ff, Dd, 8);
  }
}

// Round 26
// 663.216 us; speedup vs baseline: 1.0218x; 1.0218x over previous
//
#include <hip/hip_runtime.h>
#include <hip/hip_bf16.h>
#include <cmath>

#define LAYERS 4
#define Bb 4
#define Ss 1024
#define Dd 1024
#define Ff 2048
#define Hh 8
#define DHd 128
#define Mm (Bb * Ss)   // 4096 rows
#define EPSf 1e-5f
#define LDQ 4096       // combined QKVG row stride

typedef __attribute__((ext_vector_type(8))) short short8v;
typedef __attribute__((ext_vector_type(4))) float f32x4;
typedef __attribute__((ext_vector_type(4))) unsigned int u32x4;

__device__ __forceinline__ float swish_f(float x) { return x / (1.f + expf(-x)); }
__device__ __forceinline__ float gelu_f(float x) {
  return 0.5f * x * (1.f + tanhf(0.7978845608028654f * (x + 0.044715f * x * x * x)));
}
__device__ __forceinline__ unsigned short f2bfu(float f) {
  __hip_bfloat16 h = __float2bfloat16(f);
  return __builtin_bit_cast(unsigned short, h);
}
__device__ __forceinline__ float bfu2f(unsigned short u) {
  unsigned v = ((unsigned)u) << 16;
  return __builtin_bit_cast(float, v);
}
__device__ __forceinline__ void gl_lds16(const void* g, void* l) {
  __builtin_amdgcn_global_load_lds((__attribute__((address_space(1))) void*)g,
                                   (__attribute__((address_space(3))) void*)l, 16, 0, 0);
}
__device__ __forceinline__ f32x4 mfma16(short8v a, short8v b, f32x4 c) {
  return __builtin_amdgcn_mfma_f32_16x16x32_bf16(a, b, c, 0, 0, 0);
}

// ---------------- LayerNorm fp32 -> bf16 (standalone, used for FFN LN) ----------------
__global__ __launch_bounds__(256) void ln_bf16_kernel(const float* __restrict__ x,
                                                      short* __restrict__ outb,
                                                      const float* __restrict__ sc,
                                                      const float* __restrict__ bi) {
  const int row = blockIdx.x;
  const int t = threadIdx.x;
  const float4 v = *(const float4*)(x + (size_t)row * Dd + t * 4);
  float s = v.x + v.y + v.z + v.w;
  float s2 = v.x * v.x + v.y * v.y + v.z * v.z + v.w * v.w;
#pragma unroll
  for (int o = 32; o > 0; o >>= 1) { s += __shfl_down(s, o); s2 += __shfl_down(s2, o); }
  __shared__ float ps[4], ps2[4];
  if ((t & 63) == 0) { ps[t >> 6] = s; ps2[t >> 6] = s2; }
  __syncthreads();
  s = ps[0] + ps[1] + ps[2] + ps[3];
  s2 = ps2[0] + ps2[1] + ps2[2] + ps2[3];
  const float mu = s * (1.f / Dd);
  const float var = s2 * (1.f / Dd) - mu * mu;
  const float rstd = rsqrtf(var + EPSf);
  const float4 g = *(const float4*)(sc + t * 4);
  const float4 b = *(const float4*)(bi + t * 4);
  const float o0 = (v.x - mu) * rstd * g.x + b.x;
  const float o1 = (v.y - mu) * rstd * g.y + b.y;
  const float o2 = (v.z - mu) * rstd * g.z + b.z;
  const float o3 = (v.w - mu) * rstd * g.w + b.w;
  unsigned p0 = (unsigned)f2bfu(o0) | ((unsigned)f2bfu(o1) << 16);
  unsigned p1 = (unsigned)f2bfu(o2) | ((unsigned)f2bfu(o3) << 16);
  uint2 pk; pk.x = p0; pk.y = p1;
  *(uint2*)(outb + (size_t)row * Dd + t * 4) = pk;
}

// ---------------- RoPE tables ----------------
__global__ void rope_table_kernel(float* __restrict__ ct, float* __restrict__ st) {
  const int i = blockIdx.x * 256 + threadIdx.x;  // < Ss*64
  const int s = i >> 6, f = i & 63;
  const float inv = powf(10000.f, -(float)f / 64.f);
  const float a = (float)s * inv;
  ct[i] = cosf(a);
  st[i] = sinf(a);
}

// ---------------- merged weight transpose + LN(Acur): one dispatch (13312 blocks) --------
__global__ __launch_bounds__(256) void wtrans_ln_kernel(
    const float* __restrict__ Wq, const float* __restrict__ Wk,
    const float* __restrict__ Wv, const float* __restrict__ Wg,
    const float* __restrict__ Wo, const float* __restrict__ W1,
    const float* __restrict__ W2,
    short* __restrict__ Wqkvgt, short* __restrict__ Wot,
    short* __restrict__ W1t, short* __restrict__ W2t,
    const float* __restrict__ x, short* __restrict__ outb,
    const float* __restrict__ sc, const float* __restrict__ bi) {
  __shared__ float tile[32][33];
  __shared__ float ps[4], ps2[4];
  const int t = threadIdx.x;
  const int blk = blockIdx.x;
  if (blk >= 9216) {
    const int row = blk - 9216;
    const float4 v = *(const float4*)(x + (size_t)row * Dd + t * 4);
    float s = v.x + v.y + v.z + v.w;
    float s2 = v.x * v.x + v.y * v.y + v.z * v.z + v.w * v.w;
#pragma unroll
    for (int o = 32; o > 0; o >>= 1) { s += __shfl_down(s, o); s2 += __shfl_down(s2, o); }
    if ((t & 63) == 0) { ps[t >> 6] = s; ps2[t >> 6] = s2; }
    __syncthreads();
    s = ps[0] + ps[1] + ps[2] + ps[3];
    s2 = ps2[0] + ps2[1] + ps2[2] + ps2[3];
    const float mu = s * (1.f / Dd);
    const float var = s2 * (1.f / Dd) - mu * mu;
    const float rstd = rsqrtf(var + EPSf);
    const float4 g = *(const float4*)(sc + t * 4);
    const float4 b = *(const float4*)(bi + t * 4);
    const float o0 = (v.x - mu) * rstd * g.x + b.x;
    const float o1 = (v.y - mu) * rstd * g.y + b.y;
    const float o2 = (v.z - mu) * rstd * g.z + b.z;
    const float o3 = (v.w - mu) * rstd * g.w + b.w;
    unsigned p0 = (unsigned)f2bfu(o0) | ((unsigned)f2bfu(o1) << 16);
    unsigned p1 = (unsigned)f2bfu(o2) | ((unsigned)f2bfu(o3) << 16);
    uint2 pk; pk.x = p0; pk.y = p1;
    *(uint2*)(outb + (size_t)row * Dd + t * 4) = pk;
    return;
  }
  const int tc = t & 31, tr8 = t >> 5;
  const float* src; short* dst; int K, N, n0, k0, nl;
  if (blk < 4096) {
    const int bx = blk & 127, ky = blk >> 7;
    n0 = bx * 32; k0 = ky * 32;
    const int which = n0 >> 10;
    src = (which == 0) ? Wq : (which == 1) ? Wk : (which == 2) ? Wv : Wg;
    nl = n0 & 1023; N = 1024; K = 1024; dst = Wqkvgt;
  } else if (blk < 5120) {
    const int b2 = blk - 4096;
    n0 = (b2 & 31) * 32; k0 = (b2 >> 5) * 32; nl = n0;
    src = Wo; N = 1024; K = 1024; dst = Wot;
  } else if (blk < 7168) {
    const int b2 = blk - 5120;
    n0 = (b2 & 63) * 32; k0 = (b2 >> 6) * 32; nl = n0;
    src = W1; N = 2048; K = 1024; dst = W1t;
  } else {
    const int b2 = blk - 7168;
    n0 = (b2 & 31) * 32; k0 = (b2 >> 5) * 32; nl = n0;
    src = W2; N = 1024; K = 2048; dst = W2t;
  }
#pragma unroll
  for (int i = 0; i < 4; ++i) {
    const int r = tr8 + i * 8;
    tile[r][tc] = src[(size_t)(k0 + r) * N + nl + tc];
  }
  __syncthreads();
#pragma unroll
  for (int i = 0; i < 4; ++i) {
    const int r = tr8 + i * 8;
    dst[(size_t)(n0 + r) * K + k0 + tc] = (short)f2bfu(tile[tc][r]);
  }
}

// ---------------- bf16 MFMA GEMM v10r: 256x256 8-phase + V^T epilogue + fused RoPE -------
// Q-blocks (col0<1024) and K-blocks (1024<=col0<2048) rotate in-register in the epilogue
// (partner element via __shfl_xor(v,1); cos/sin from tables). rope_qk dispatch deleted.
template <int EPI>
__global__ __launch_bounds__(512, 2) void gemm10(const short* __restrict__ A,
                                                 const short* __restrict__ Bt,
                                                 float* __restrict__ Cf,
                                                 short* __restrict__ Cb,
                                                 const float* __restrict__ Res,
                                                 short* __restrict__ Vt,
                                                 const float* __restrict__ ct,
                                                 const float* __restrict__ st,
                                                 int N, int K, int ldc) {
  __shared__ __align__(16) short SM[65536];   // 128 KB: As = SM[0..32767], Bs = SM[32768..]
  const int t = threadIdx.x;
  const int w = t >> 6, l = t & 63;
  const int lq = l >> 4, lr = l & 15;
  const int wr = w >> 2, wc = w & 3;
  const int bhalf = wc >> 1, brow0 = (wc & 1) * 64;
  const int nwg = gridDim.x * gridDim.y;
  const int bid0 = blockIdx.x + blockIdx.y * gridDim.x;
  const int lgid = (bid0 & 7) * (nwg >> 3) + (bid0 >> 3);
  const int bx = lgid % gridDim.x, by = lgid / gridDim.x;
  const int row0 = by * 256, col0 = bx * 256;
  const int NT = K >> 6;

  f32x4 acc[8][4] = {};
  short8v a[4][2], b[4][2];

  auto stageA = [&](int kt, int hf) {
    const int db = kt & 1;
    short* dstb = SM + (db * 2 + hf) * 8192;
#pragma unroll
    for (int i = 0; i < 2; ++i) {
      const int c = t + i * 512;
      const int row = c >> 3, slot = c & 7;
      gl_lds16(A + (size_t)(row0 + hf * 128 + row) * K + kt * 64 + ((slot ^ (row & 7)) << 3),
               dstb + c * 8);
    }
  };
  auto stageB = [&](int kt, int hf) {
    const int db = kt & 1;
    short* dstb = SM + 32768 + (db * 2 + hf) * 8192;
#pragma unroll
    for (int i = 0; i < 2; ++i) {
      const int c = t + i * 512;
      const int row = c >> 3, slot = c & 7;
      gl_lds16(Bt + (size_t)(col0 + hf * 128 + row) * K + kt * 64 + ((slot ^ (row & 7)) << 3),
               dstb + c * 8);
    }
  };
  auto rdA = [&](int db, int m, int ks) -> short8v {
    const int row = m * 16 + lr;
    return *(const short8v*)(SM + (db * 2 + wr) * 8192 + row * 64 +
                             (((ks << 2) + lq) ^ (row & 7)) * 8);
  };
  auto rdB = [&](int db, int n, int ks) -> short8v {
    const int row = brow0 + n * 16 + lr;
    return *(const short8v*)(SM + 32768 + (db * 2 + bhalf) * 8192 + row * 64 +
                             (((ks << 2) + lq) ^ (row & 7)) * 8);
  };

  stageA(0, 0); stageA(0, 1); stageB(0, 0); stageB(0, 1);
  if (NT > 1) { stageB(1, 0); stageB(1, 1); }
  if (NT > 1) { asm volatile("s_waitcnt vmcnt(4)" ::: "memory"); }
  else        { asm volatile("s_waitcnt vmcnt(0)" ::: "memory"); }
  asm volatile("s_barrier" ::: "memory");

  for (int kt = 0; kt < NT; ++kt) {
    const int db = kt & 1;
#pragma unroll
    for (int m = 0; m < 4; ++m) { a[m][0] = rdA(db, m, 0); a[m][1] = rdA(db, m, 1); }
#pragma unroll
    for (int n = 0; n < 2; ++n) { b[n][0] = rdB(db, n, 0); b[n][1] = rdB(db, n, 1); }
    if (kt + 1 < NT) stageA(kt + 1, 0);
    __builtin_amdgcn_s_setprio(1);
#pragma unroll
    for (int m = 0; m < 4; ++m)
#pragma unroll
      for (int n = 0; n < 2; ++n) {
        acc[m][n] = mfma16(a[m][0], b[n][0], acc[m][n]);
        acc[m][n] = mfma16(a[m][1], b[n][1], acc[m][n]);
      }
    __builtin_amdgcn_s_setprio(0);
    asm volatile("s_barrier" ::: "memory");
#pragma unroll
    for (int n = 2; n < 4; ++n) { b[n][0] = rdB(db, n, 0); b[n][1] = rdB(db, n, 1); }
    if (kt + 1 < NT) stageA(kt + 1, 1);
    __builtin_amdgcn_s_setprio(1);
#pragma unroll
    for (int m = 0; m < 4; ++m)
#pragma unroll
      for (int n = 2; n < 4; ++n) {
        acc[m][n] = mfma16(a[m][0], b[n][0], acc[m][n]);
        acc[m][n] = mfma16(a[m][1], b[n][1], acc[m][n]);
      }
    __builtin_amdgcn_s_setprio(0);
    asm volatile("s_barrier" ::: "memory");
#pragma unroll
    for (int m = 0; m < 4; ++m) { a[m][0] = rdA(db, m + 4, 0); a[m][1] = rdA(db, m + 4, 1); }
    if (kt + 2 < NT) stageB(kt + 2, 0);
    __builtin_amdgcn_s_setprio(1);
#pragma unroll
    for (int m = 0; m < 4; ++m)
#pragma unroll
      for (int n = 0; n < 2; ++n) {
        acc[m + 4][n] = mfma16(a[m][0], b[n][0], acc[m + 4][n]);
        acc[m + 4][n] = mfma16(a[m][1], b[n][1], acc[m + 4][n]);
      }
    __builtin_amdgcn_s_setprio(0);
    asm volatile("s_barrier" ::: "memory");
    if (kt + 2 < NT) stageB(kt + 2, 1);
    __builtin_amdgcn_s_setprio(1);
#pragma unroll
    for (int m = 0; m < 4; ++m)
#pragma unroll
      for (int n = 2; n < 4; ++n) {
        acc[m + 4][n] = mfma16(a[m][0], b[n][0], acc[m + 4][n]);
        acc[m + 4][n] = mfma16(a[m][1], b[n][1], acc[m + 4][n]);
      }
    __builtin_amdgcn_s_setprio(0);
    if (kt + 2 < NT) { asm volatile("s_waitcnt vmcnt(4)" ::: "memory"); }
    else             { asm volatile("s_waitcnt vmcnt(0)" ::: "memory"); }
    asm volatile("s_barrier" ::: "memory");
  }

  if (EPI == 0 && col0 >= 2048 && col0 < 3072) {
    // V-block: transpose through (now dead) LDS, write Vt directly.
#pragma unroll
    for (int m = 0; m < 8; ++m)
#pragma unroll
      for (int n = 0; n < 4; ++n)
#pragma unroll
        for (int r = 0; r < 4; ++r) {
          const int ls = wr * 128 + m * 16 + lq * 4 + r;  // local s
          const int ld = wc * 64 + n * 16 + lr;           // local d
          SM[ld * 256 + ((((ls >> 3) ^ (ld & 31)) << 3) | (ls & 7))] =
              (short)f2bfu(acc[m][n][r]);
        }
    __syncthreads();
    const int bI = row0 >> 10;
    const int s0g = row0 & 1023;
#pragma unroll 4
    for (int rr = 0; rr < 32; ++rr) {
      const int dl = w * 32 + rr;
      const int gcol = (col0 - 2048) + dl;   // 0..1023
      const int hh = gcol >> 7, dh = gcol & 127;
      unsigned pk0, pk1;
      {
        const int s0 = l * 4;
        const unsigned short e0 =
            (unsigned short)SM[dl * 256 + ((((s0 + 0) >> 3) ^ (dl & 31)) << 3 | ((s0 + 0) & 7))];
        const unsigned short e1 =
            (unsigned short)SM[dl * 256 + ((((s0 + 1) >> 3) ^ (dl & 31)) << 3 | ((s0 + 1) & 7))];
        const unsigned short e2 =
            (unsigned short)SM[dl * 256 + ((((s0 + 2) >> 3) ^ (dl & 31)) << 3 | ((s0 + 2) & 7))];
        const unsigned short e3 =
            (unsigned short)SM[dl * 256 + ((((s0 + 3) >> 3) ^ (dl & 31)) << 3 | ((s0 + 3) & 7))];
        pk0 = (unsigned)e0 | ((unsigned)e1 << 16);
        pk1 = (unsigned)e2 | ((unsigned)e3 << 16);
      }
      uint2 pk; pk.x = pk0; pk.y = pk1;
      *(uint2*)(Vt + ((size_t)((bI * 8 + hh) * 128 + dh)) * Ss + s0g + l * 4) = pk;
    }
    return;
  }

  if (EPI == 0 && col0 < 2048) {
    // Q/K-block: fused RoPE in-register (pair element lives in lane l^1, same (m,n,r)).
    const bool isQ = (col0 < 1024);
    const int odd = lr & 1;
#pragma unroll
    for (int m = 0; m < 8; ++m) {
#pragma unroll
      for (int n = 0; n < 4; ++n) {
#pragma unroll
        for (int r = 0; r < 4; ++r) {
          const int row = row0 + wr * 128 + m * 16 + lq * 4 + r;
          const int col = col0 + wc * 64 + n * 16 + lr;
          const float v = acc[m][n][r];
          const float px = __shfl_xor(v, 1);
          const int spos = row & (Ss - 1);
          const int f = (col >> 1) & 63;
          const float cc = ct[(spos << 6) + f];
          const float sn = st[(spos << 6) + f];
          float ov;
          if (isQ) ov = v * cc + (odd ? px * sn : -px * sn);
          else     ov = v * cc + (odd ? -px * sn : px * sn);
          Cb[(size_t)row * ldc + col] = (short)f2bfu(ov);
        }
      }
    }
    return;
  }

#pragma unroll
  for (int m = 0; m < 8; ++m) {
#pragma unroll
    for (int n = 0; n < 4; ++n) {
#pragma unroll
      for (int r = 0; r < 4; ++r) {
        const int row = row0 + wr * 128 + m * 16 + lq * 4 + r;
        const int col = col0 + wc * 64 + n * 16 + lr;
        const size_t o = (size_t)row * ldc + col;
        float v = acc[m][n][r];
        if (EPI == 0) Cb[o] = (short)f2bfu(v);
        else if (EPI == 1) Cf[o] = v + Res[o];
        else Cb[o] = (short)f2bfu(gelu_f(v));
      }
    }
  }
}

// ---------------- bf16 MFMA GEMM v11: 256x128 2-phase/K-tile, ring-3 LDS, vmcnt(6) --------
template <int EPI>
__global__ __launch_bounds__(512) void gemm11(const short* __restrict__ A,
                                              const short* __restrict__ Bt,
                                              float* __restrict__ Cf,
                                              short* __restrict__ Cb,
                                              const float* __restrict__ Res,
                                              int K, int lda, int ldb, int ldc, int nxt) {
  __shared__ __align__(16) short As[3][256 * 64];  // 96 KB ring-3
  __shared__ __align__(16) short Bs[3][128 * 64];  // 48 KB ring-3
  const int t = threadIdx.x;
  const int w = t >> 6, l = t & 63;
  const int lq = l >> 4, lr = l & 15;
  const int wr = w >> 2, wc = w & 3;
  const int nwg = gridDim.x;
  const int lgid = (blockIdx.x & 7) * (nwg >> 3) + (blockIdx.x >> 3);
  const int mt = lgid / nxt, nt_ = lgid % nxt;
  const int row0 = mt * 256, col0 = nt_ * 128;
  const int NT = K >> 6;
  f32x4 acc[8][2] = {};
  short8v a[4][2], b[2][2];

  auto stageA = [&](int kt, int hf) {
    const int s = kt % 3;
#pragma unroll
    for (int i = 0; i < 2; ++i) {
      const int c = t + i * 512;
      const int row = c >> 3, slot = c & 7;
      gl_lds16(A + (size_t)(row0 + hf * 128 + row) * lda + kt * 64 + ((slot ^ (row & 7)) << 3),
               &As[s][hf * 8192 + c * 8]);
    }
  };
  auto stageB = [&](int kt) {
    const int s = kt % 3;
#pragma unroll
    for (int i = 0; i < 2; ++i) {
      const int c = t + i * 512;
      const int row = c >> 3, slot = c & 7;
      gl_lds16(Bt + (size_t)(col0 + row) * ldb + kt * 64 + ((slot ^ (row & 7)) << 3),
               &Bs[s][c * 8]);
    }
  };
  auto rdA = [&](int s, int m, int ks) -> short8v {
    const int row = wr * 128 + m * 16 + lr;
    return *(const short8v*)&As[s][row * 64 + (((ks << 2) + lq) ^ (row & 7)) * 8];
  };
  auto rdB = [&](int s, int n, int ks) -> short8v {
    const int row = wc * 32 + n * 16 + lr;
    return *(const short8v*)&Bs[s][row * 64 + (((ks << 2) + lq) ^ (row & 7)) * 8];
  };

  stageA(0, 0); stageA(0, 1); stageB(0);
  stageA(1, 0); stageA(1, 1); stageB(1);
  asm volatile("s_waitcnt vmcnt(6)" ::: "memory");
  asm volatile("s_barrier" ::: "memory");

  for (int kt = 0; kt < NT; ++kt) {
    const int s = kt % 3;
#pragma unroll
    for (int m = 0; m < 4; ++m) { a[m][0] = rdA(s, m, 0); a[m][1] = rdA(s, m, 1); }
#pragma unroll
    for (int n = 0; n < 2; ++n) { b[n][0] = rdB(s, n, 0); b[n][1] = rdB(s, n, 1); }
    if (kt + 2 < NT) stageA(kt + 2, 0);
    __builtin_amdgcn_s_setprio(1);
#pragma unroll
    for (int m = 0; m < 4; ++m)
#pragma unroll
      for (int n = 0; n < 2; ++n) {
        acc[m][n] = mfma16(a[m][0], b[n][0], acc[m][n]);
        acc[m][n] = mfma16(a[m][1], b[n][1], acc[m][n]);
      }
    __builtin_amdgcn_s_setprio(0);
    asm volatile("s_barrier" ::: "memory");
#pragma unroll
    for (int m = 0; m < 4; ++m) { a[m][0] = rdA(s, m + 4, 0); a[m][1] = rdA(s, m + 4, 1); }
    if (kt + 2 < NT) { stageA(kt + 2, 1); stageB(kt + 2); }
    __builtin_amdgcn_s_setprio(1);
#pragma unroll
    for (int m = 0; m < 4; ++m)
#pragma unroll
      for (int n = 0; n < 2; ++n) {
        acc[m + 4][n] = mfma16(a[m][0], b[n][0], acc[m + 4][n]);
        acc[m + 4][n] = mfma16(a[m][1], b[n][1], acc[m + 4][n]);
      }
    __builtin_amdgcn_s_setprio(0);
    if (kt + 2 < NT) { asm volatile("s_waitcnt vmcnt(6)" ::: "memory"); }
    else             { asm volatile("s_waitcnt vmcnt(0)" ::: "memory"); }
    asm volatile("s_barrier" ::: "memory");
  }

#pragma unroll
  for (int m = 0; m < 8; ++m) {
#pragma unroll
    for (int n = 0; n < 2; ++n) {
#pragma unroll
      for (int r = 0; r < 4; ++r) {
        const int row = row0 + wr * 128 + m * 16 + lq * 4 + r;
        const int col = col0 + wc * 32 + n * 16 + lr;
        const size_t o = (size_t)row * ldc + col;
        float v = acc[m][n][r];
        if (EPI == 0) Cb[o] = (short)f2bfu(v);
        else if (EPI == 1) Cf[o] = v + Res[o];
        else Cb[o] = (short)f2bfu(gelu_f(v));
      }
    }
  }
}

// ---------------- bf16 MFMA GEMM v12: 128x128 2-phase/K-tile, ring-3 LDS, vmcnt(4) --------
template <int EPI>
__global__ __launch_bounds__(512) void gemm12(const short* __restrict__ A,
                                              const short* __restrict__ Bt,
                                              float* __restrict__ Cf,
                                              short* __restrict__ Cb,
                                              const float* __restrict__ Res,
                                              int K, int lda, int ldb, int ldc, int nxt) {
  __shared__ __align__(16) short As[3][128 * 64];  // 48 KB ring-3
  __shared__ __align__(16) short Bs[3][128 * 64];  // 48 KB ring-3
  const int t = threadIdx.x;
  const int w = t >> 6, l = t & 63;
  const int lq = l >> 4, lr = l & 15;
  const int wr = w >> 2, wc = w & 3;
  const int nwg = gridDim.x;
  const int lgid = (blockIdx.x & 7) * (nwg >> 3) + (blockIdx.x >> 3);
  const int mt = lgid / nxt, nt_ = lgid % nxt;
  const int row0 = mt * 128, col0 = nt_ * 128;
  const int NT = K >> 6;
  f32x4 acc[4][2] = {};
  short8v a[4][2], b[2][2];

  auto stageA = [&](int kt) {
    const int s = kt % 3;
#pragma unroll
    for (int i = 0; i < 2; ++i) {
      const int c = t + i * 512;
      const int row = c >> 3, slot = c & 7;
      gl_lds16(A + (size_t)(row0 + row) * lda + kt * 64 + ((slot ^ (row & 7)) << 3),
               &As[s][c * 8]);
    }
  };
  auto stageB = [&](int kt) {
    const int s = kt % 3;
#pragma unroll
    for (int i = 0; i < 2; ++i) {
      const int c = t + i * 512;
      const int row = c >> 3, slot = c & 7;
      gl_lds16(Bt + (size_t)(col0 + row) * ldb + kt * 64 + ((slot ^ (row & 7)) << 3),
               &Bs[s][c * 8]);
    }
  };
  auto rdA = [&](int s, int m, int ks) -> short8v {
    const int row = wr * 64 + m * 16 + lr;
    return *(const short8v*)&As[s][row * 64 + (((ks << 2) + lq) ^ (row & 7)) * 8];
  };
  auto rdB = [&](int s, int n, int ks) -> short8v {
    const int row = wc * 32 + n * 16 + lr;
    return *(const short8v*)&Bs[s][row * 64 + (((ks << 2) + lq) ^ (row & 7)) * 8];
  };

  stageA(0); stageB(0);
  stageA(1); stageB(1);
  asm volatile("s_waitcnt vmcnt(4)" ::: "memory");
  asm volatile("s_barrier" ::: "memory");

  for (int kt = 0; kt < NT; ++kt) {
    const int s = kt % 3;
#pragma unroll
    for (int m = 0; m < 4; ++m) { a[m][0] = rdA(s, m, 0); a[m][1] = rdA(s, m, 1); }
#pragma unroll
    for (int n = 0; n < 2; ++n) { b[n][0] = rdB(s, n, 0); b[n][1] = rdB(s, n, 1); }
    if (kt + 2 < NT) stageA(kt + 2);
    __builtin_amdgcn_s_setprio(1);
#pragma unroll
    for (int m = 0; m < 2; ++m)
#pragma unroll
      for (int n = 0; n < 2; ++n) {
        acc[m][n] = mfma16(a[m][0], b[n][0], acc[m][n]);
        acc[m][n] = mfma16(a[m][1], b[n][1], acc[m][n]);
      }
    __builtin_amdgcn_s_setprio(0);
    asm volatile("s_barrier" ::: "memory");
    if (kt + 2 < NT) stageB(kt + 2);
    __builtin_amdgcn_s_setprio(1);
#pragma unroll
    for (int m = 2; m < 4; ++m)
#pragma unroll
      for (int n = 0; n < 2; ++n) {
        acc[m][n] = mfma16(a[m][0], b[n][0], acc[m][n]);
        acc[m][n] = mfma16(a[m][1], b[n][1], acc[m][n]);
      }
    __builtin_amdgcn_s_setprio(0);
    if (kt + 2 < NT) { asm volatile("s_waitcnt vmcnt(4)" ::: "memory"); }
    else             { asm volatile("s_waitcnt vmcnt(0)" ::: "memory"); }
    asm volatile("s_barrier" ::: "memory");
  }

#pragma unroll
  for (int m = 0; m < 4; ++m) {
#pragma unroll
    for (int n = 0; n < 2; ++n) {
#pragma unroll
      for (int r = 0; r < 4; ++r) {
        const int row = row0 + wr * 64 + m * 16 + lq * 4 + r;
        const int col = col0 + wc * 32 + n * 16 + lr;
        const size_t o = (size_t)row * ldc + col;
        float v = acc[m][n][r];
        if (EPI == 0) Cb[o] = (short)f2bfu(v);
        else if (EPI == 1) Cf[o] = v + Res[o];
        else Cb[o] = (short)f2bfu(gelu_f(v));
      }
    }
  }
}

// ---------------- Retention v5: fused GN+gate, paired q-blocks (qb,15-qb), QBLK=64 --------
__global__ __launch_bounds__(256) void ret5_kernel(const short* __restrict__ QKVGb,
                                                   const short* __restrict__ Vt,
                                                   short* __restrict__ Gb,
                                                   const float* __restrict__ gs,
                                                   const float* __restrict__ gb) {
  __shared__ __align__(16) short Ks[2][64 * 128];
  __shared__ __align__(16) short Vs[2][128 * 64];
  const int t = threadIdx.x, w = t >> 6, l = t & 63;
  const int lq = l >> 4, lr = l & 15;
  const int u = blockIdx.x;                     // 0..255
  const int lgid = (u & 7) * 32 + (u >> 3);     // XCD-contiguous
  const int bh = lgid >> 3, pr = lgid & 7;
  const int b = bh >> 3, h = bh & 7;
  const float lstep = (logf(1.f / 512.f) - logf(1.f / 32.f)) * (1.f / 7.f);
  const float gamma = 1.f - expf(logf(1.f / 32.f) + (float)h * lstep);
  const float l2g = logf(gamma) * 1.44269504f;
  const short* Qp = QKVGb;
  const short* Kp = QKVGb + 1024;

  float cmf[4], csr[4];
#pragma unroll
  for (int mf = 0; mf < 4; ++mf) cmf[mf] = exp2f(l2g * (float)(-16 * mf));
#pragma unroll
  for (int r = 0; r < 4; ++r) csr[r] = exp2f(l2g * (float)(63 - 4 * lq - r));
  float gsv[8], gbv[8];
#pragma unroll
  for (int nd = 0; nd < 8; ++nd) {
    gsv[nd] = gs[h * DHd + nd * 16 + lr];
    gbv[nd] = gb[h * DHd + nd * 16 + lr];
  }
  const int sb = ((lq & 1) * 2) * 16 + lr;

  auto stageKV = [&](int m0, int buf) {
#pragma unroll
    for (int i = 0; i < 4; ++i) {
      const int c = (w * 4 + i) * 64 + l;
      const int row = c >> 4, slot = c & 15;
      gl_lds16(Kp + (size_t)(b * Ss + m0 + row) * LDQ + h * DHd + ((slot ^ (row & 7)) * 8),
               &Ks[buf][(w * 4 + i) * 512]);
    }
#pragma unroll
    for (int i = 0; i < 4; ++i) {
      const int c = (w * 4 + i) * 64 + l;
      const int row = c >> 3, slot = c & 7;
      gl_lds16(Vt + (size_t)(bh * DHd + row) * Ss + m0 + ((slot ^ (row & 7)) * 8),
               &Vs[buf][(w * 4 + i) * 512]);
    }
  };

  for (int pass = 0; pass < 2; ++pass) {
    const int qb = pass ? (15 - pr) : pr;
    const int q0 = qb * 64;
    const int nt = qb + 1;
    short8v qf[4];
#pragma unroll
    for (int ks = 0; ks < 4; ++ks)
      qf[ks] = *(const short8v*)(Qp + (size_t)(b * Ss + q0 + w * 16 + lr) * LDQ +
                                 h * DHd + ks * 32 + lq * 8);
    f32x4 yacc[8] = {};
    stageKV(0, 0);
    __syncthreads();
    int cur = 0;
    for (int tt = 0; tt < nt; ++tt) {
      const int m0 = tt * 64;
      if (tt + 1 < nt) stageKV((tt + 1) * 64, cur ^ 1);

      f32x4 st[4] = {};
      __builtin_amdgcn_s_setprio(1);
#pragma unroll
      for (int mf = 0; mf < 4; ++mf) {
        const int row = mf * 16 + lr;
#pragma unroll
        for (int ks = 0; ks < 4; ++ks) {
          short8v kf = *(const short8v*)&Ks[cur][row * 128 + (((4 * ks + lq) ^ (row & 7)) * 8)];
          st[mf] = mfma16(kf, qf[ks], st[mf]);
        }
      }
      __builtin_amdgcn_s_setprio(0);
      const int qg = q0 + w * 16 + lr;
      const float rs = exp2f(l2g * (float)(qg - m0 - 63));
#pragma unroll
      for (int mf = 0; mf < 4; ++mf)
#pragma unroll
        for (int r = 0; r < 4; ++r) {
          const int kvg = m0 + mf * 16 + lq * 4 + r;
          const float wgt = (qg >= kvg) ? rs * cmf[mf] * csr[r] : 0.f;
          st[mf][r] *= wgt;
        }
      unsigned pk[4][2];
#pragma unroll
      for (int mf = 0; mf < 4; ++mf)
#pragma unroll
        for (int p = 0; p < 2; ++p)
          pk[mf][p] = (unsigned)f2bfu(st[mf][2 * p]) |
                      ((unsigned)f2bfu(st[mf][2 * p + 1]) << 16);
      short8v afr[2];
#pragma unroll
      for (int ks2 = 0; ks2 < 2; ++ks2) {
        u32x4 wd;
#pragma unroll
        for (int wj = 0; wj < 4; ++wj) {
          const int src = sb + (wj >> 1) * 16;
          const unsigned v0 = __shfl(pk[2 * ks2 + 0][wj & 1], src);
          const unsigned v1 = __shfl(pk[2 * ks2 + 1][wj & 1], src);
          wd[wj] = (lq >= 2) ? v1 : v0;
        }
        afr[ks2] = __builtin_bit_cast(short8v, wd);
      }
      __builtin_amdgcn_s_setprio(1);
#pragma unroll
      for (int nd = 0; nd < 8; ++nd) {
        const int row = nd * 16 + lr;
#pragma unroll
        for (int ks2 = 0; ks2 < 2; ++ks2) {
          short8v vf = *(const short8v*)&Vs[cur][row * 64 + (((4 * ks2 + lq) ^ (row & 7)) * 8)];
          yacc[nd] = mfma16(afr[ks2], vf, yacc[nd]);
        }
      }
      __builtin_amdgcn_s_setprio(0);
      __syncthreads();
      cur ^= 1;
    }
    // fused GroupNorm + gate epilogue
#pragma unroll
    for (int r = 0; r < 4; ++r) {
      float s1 = 0.f, s2 = 0.f;
#pragma unroll
      for (int nd = 0; nd < 8; ++nd) { const float v = yacc[nd][r]; s1 += v; s2 += v * v; }
#pragma unroll
      for (int msk = 1; msk < 16; msk <<= 1) {
        s1 += __shfl_xor(s1, msk);
        s2 += __shfl_xor(s2, msk);
      }
      const float mu = s1 * (1.f / 128.f);
      const float rstd = rsqrtf(s2 * (1.f / 128.f) - mu * mu + EPSf);
      const int q = q0 + w * 16 + lq * 4 + r;
      const size_t gbase = (size_t)(b * Ss + q) * LDQ + 3072 + h * DHd;
      const size_t obase = (size_t)(b * Ss + q) * Dd + h * DHd;
#pragma unroll
      for (int nd = 0; nd < 8; ++nd) {
        const int d = nd * 16 + lr;
        const float yv = (yacc[nd][r] - mu) * rstd * gsv[nd] + gbv[nd];
        const float gvx = bfu2f((unsigned short)QKVGb[gbase + d]);
        Gb[obase + d] = (short)f2bfu(swish_f(gvx) * yv);
      }
    }
  }
}

extern "C" void kernel_launch(void* const* d_in, const int* in_sizes, int n_in,
                              void* d_out, int out_size, void* d_ws, size_t ws_size,
                              hipStream_t stream) {
  const float* X = (const float*)d_in[0];
  const float* Wq = (const float*)d_in[1];
  const float* Wk = (const float*)d_in[2];
  const float* Wv = (const float*)d_in[3];
  const float* Wg = (const float*)d_in[4];
  const float* Wo = (const float*)d_in[5];
  const float* W1 = (const float*)d_in[6];
  const float* W2 = (const float*)d_in[7];
  const float* lns = (const float*)d_in[8];
  const float* lnb = (const float*)d_in[9];
  const float* gns = (const float*)d_in[10];
  const float* gnb = (const float*)d_in[11];
  float* out = (float*)d_out;

  char* W = (char*)d_ws;
  const size_t MB = 1u << 20;
  float* Abuf  = (float*)(W);             // 16 MB fp32
  short* Xnb   = (short*)(W + 16 * MB);   // 8 MB bf16
  short* QKVGb = (short*)(W + 24 * MB);   // 32 MB bf16 [4096][4096]; Hb aliases first 16 MB
  short* Vtb   = (short*)(W + 88 * MB);   // 8 MB bf16
  short* Gb    = (short*)(W + 96 * MB);   // 8 MB bf16
  short* Wqkvgt= (short*)(W + 104 * MB);  // 8 MB
  short* Wot   = (short*)(W + 112 * MB);  // 2 MB
  short* W1t   = (short*)(W + 114 * MB);  // 4 MB
  short* W2t   = (short*)(W + 118 * MB);  // 4 MB
  float* ct    = (float*)(W + 122 * MB);  // 256 KB
  float* st    = ct + Ss * 64;            // 256 KB
  short* Hb = QKVGb;  // FFN hidden 4096x2048 bf16 (16 MB)

  rope_table_kernel<<<(Ss * 64) / 256, 256, 0, stream>>>(ct, st);

  for (int l = 0; l < LAYERS; ++l) {
    const size_t DD = (size_t)Dd * Dd;
    const float* Acur = (l == 0) ? X : Abuf;  // residual stream input for this layer
    // merged: weight transposes + LN(Acur) in one dispatch
    wtrans_ln_kernel<<<13312, 256, 0, stream>>>(Wq + l * DD, Wk + l * DD, Wv + l * DD,
                                                Wg + l * DD, Wo + l * DD,
                                                W1 + (size_t)l * Dd * Ff,
                                                W2 + (size_t)l * Ff * Dd,
                                                Wqkvgt, Wot, W1t, W2t,
                                                Acur, Xnb, lns, lnb);
    // fused QKVG projection (8-phase 256x256) + V^T epilogue + fused RoPE on Q/K
    gemm10<0><<<dim3(16, 16), 512, 0, stream>>>(Xnb, Wqkvgt, nullptr, QKVGb,
                                                nullptr, Vtb, ct, st, 4096, Dd, LDQ);
    // retention + fused GN/gate -> Gb (bf16)
    ret5_kernel<<<256, 256, 0, stream>>>(QKVGb, Vtb, Gb,
                                         gns + (size_t)l * Dd, gnb + (size_t)l * Dd);
    // A = (Gb @ Wo) + Acur
    gemm12<1><<<256, 512, 0, stream>>>(Gb, Wot, Abuf, nullptr, Acur,
                                       Dd, Dd, Dd, Dd, 8);
    // FFN
    ln_bf16_kernel<<<Mm, 256, 0, stream>>>(Abuf, Xnb, lns, lnb);
    gemm11<2><<<256, 512, 0, stream>>>(Xnb, W1t, nullptr, Hb, nullptr,
                                       Dd, Dd, Dd, Ff, 16);
    float* dst = (l == LAYERS - 1) ? out : Abuf;
    gemm12<1><<<256, 512, 0, stream>>>(Hb, W2t, dst, nullptr, Abuf,
                                       Ff, Ff, Ff, Dd, 8);
  }
}